// Round 19
// baseline (798.676 us; speedup 1.0000x reference)
//
#include <hip/hip_runtime.h>
#include <math.h>
#include <stdint.h>

#define B_SZ    1024
#define N_TRAIN 100000
#define N_PAD   100096       // 782 tiles * 128 (permuted-position row stride)
#define D_DIM   256
#define NN      128
#define KSEL    256          // candidate count (margin 128 ranks over 128)
#define CAP     2048         // k2 collect buffer
#define NSAMP   1024         // k2 sample count
#define SRANK   8            // k2 sample threshold rank (of NSAMP) -> E[cnt]~780

typedef unsigned short u16;
typedef unsigned long long u64;
typedef __attribute__((ext_vector_type(8))) short short8v;
typedef __attribute__((ext_vector_type(4))) float f32x4;

__device__ inline u16 f2bf(float f) {
    unsigned u = __float_as_uint(f);
    return (u16)((u + 0x7FFFu + ((u >> 16) & 1u)) >> 16);
}
__device__ inline float bf2f(u16 h) { return __uint_as_float((unsigned)h << 16); }

// ---------------- Kprep: fused norms + bf16 hi/lo split (one pass over inputs) --
__global__ __launch_bounds__(256) void kprep(const float* __restrict__ trainX,
                                             const float* __restrict__ x,
                                             float* __restrict__ tt,
                                             float* __restrict__ xx,
                                             u16* __restrict__ Bh,
                                             u16* __restrict__ Bl,
                                             u16* __restrict__ Ah) {
    int wave = (blockIdx.x * blockDim.x + threadIdx.x) >> 6;
    int lane = threadIdx.x & 63;
    if (wave >= N_TRAIN + B_SZ) return;
    const bool isTrain = wave < N_TRAIN;
    const float* row = isTrain ? (trainX + (size_t)wave * D_DIM)
                               : (x + (size_t)(wave - N_TRAIN) * D_DIM);
    float4 v = ((const float4*)row)[lane];
    float s = v.x*v.x + v.y*v.y + v.z*v.z + v.w*v.w;
    for (int off = 32; off; off >>= 1) s += __shfl_down(s, off, 64);
    u16 h0 = f2bf(v.x), h1 = f2bf(v.y), h2 = f2bf(v.z), h3 = f2bf(v.w);
    u64 hp = (u64)h0 | ((u64)h1 << 16) | ((u64)h2 << 32) | ((u64)h3 << 48);
    if (isTrain) {
        ((u64*)(Bh + (size_t)wave * D_DIM))[lane] = hp;
        u16 l0 = f2bf(v.x - bf2f(h0)), l1 = f2bf(v.y - bf2f(h1));
        u16 l2 = f2bf(v.z - bf2f(h2)), l3 = f2bf(v.w - bf2f(h3));
        ((u64*)(Bl + (size_t)wave * D_DIM))[lane] =
            (u64)l0 | ((u64)l1 << 16) | ((u64)l2 << 32) | ((u64)l3 << 48);
        if (lane == 0) tt[wave] = s;
    } else {
        ((u64*)(Ah + (size_t)(wave - N_TRAIN) * D_DIM))[lane] = hp;
        if (lane == 0) xx[wave - N_TRAIN] = s;
    }
}

// ---------------- K1m: bf16 MFMA GEMM -> approx sq distances (u16, permuted) ----
__global__ __launch_bounds__(256) void k1m(const u16* __restrict__ Ah,
                                           const u16* __restrict__ Bh,
                                           const float* __restrict__ xx,
                                           const float* __restrict__ tt,
                                           u16* __restrict__ distu,
                                           int row0, int nrows) {
    __shared__ u16 Als[4][128][8];    // [kslot][row][8 bf16] -> 16B chunks
    __shared__ u16 Bls[4][128][8];
    const int tid = threadIdx.x;
    const int lane = tid & 63, wv = tid >> 6;
    const int wr = wv >> 1, wc = wv & 1;
    const int ib = blockIdx.y * 128;
    const size_t jb = (size_t)blockIdx.x * 128;

    f32x4 acc[4][4];
    #pragma unroll
    for (int m = 0; m < 4; ++m)
        #pragma unroll
        for (int n = 0; n < 4; ++n)
            #pragma unroll
            for (int r = 0; r < 4; ++r) acc[m][n][r] = 0.f;

    for (int k0 = 0; k0 < D_DIM; k0 += 32) {
        #pragma unroll
        for (int r = 0; r < 2; ++r) {
            int c = tid + r * 256;            // 0..511
            int row = c >> 2, ks = c & 3;
            uint4 va = make_uint4(0, 0, 0, 0);
            if (ib + row < nrows)
                va = *(const uint4*)(Ah + (size_t)(row0 + ib + row) * D_DIM + k0 + ks * 8);
            *(uint4*)(&Als[ks][row][0]) = va;
            uint4 vb = make_uint4(0, 0, 0, 0);
            if (jb + row < N_TRAIN)
                vb = *(const uint4*)(Bh + (jb + row) * D_DIM + k0 + ks * 8);
            *(uint4*)(&Bls[ks][row][0]) = vb;
        }
        __syncthreads();
        const int ksl = lane >> 4, li = lane & 15;
        short8v a[4], b[4];
        #pragma unroll
        for (int m = 0; m < 4; ++m)
            a[m] = *(const short8v*)&Als[ksl][wr * 64 + m * 16 + li][0];
        #pragma unroll
        for (int n = 0; n < 4; ++n)
            b[n] = *(const short8v*)&Bls[ksl][wc * 64 + n * 16 + li][0];
        #pragma unroll
        for (int m = 0; m < 4; ++m)
            #pragma unroll
            for (int n = 0; n < 4; ++n)
                acc[m][n] = __builtin_amdgcn_mfma_f32_16x16x32_bf16(a[m], b[n], acc[m][n], 0, 0, 0);
        __syncthreads();
    }
    // epilogue: C row = (lane>>4)*4 + reg, col = lane&15; packed u64 permuted store
    const int li = lane & 15, lh = lane >> 4;
    float ttv[4]; int cols[4];
    #pragma unroll
    for (int n = 0; n < 4; ++n) {
        cols[n] = (int)jb + wc * 64 + n * 16 + li;
        ttv[n] = (cols[n] < N_TRAIN) ? tt[cols[n]] : 0.f;
    }
    #pragma unroll
    for (int m = 0; m < 4; ++m)
        #pragma unroll
        for (int r = 0; r < 4; ++r) {
            int rl = ib + wr * 64 + m * 16 + lh * 4 + r;
            if (rl >= nrows) continue;
            float xi = xx[row0 + rl];
            u64 pk = 0;
            #pragma unroll
            for (int n = 0; n < 4; ++n) {
                u16 code = 0xFFFFu;
                if (cols[n] < N_TRAIN)
                    code = f2bf(fmaxf(xi + ttv[n] - 2.0f * acc[m][n][r], 0.f));
                pk |= (u64)code << (16 * n);
            }
            *(u64*)(distu + (size_t)rl * N_PAD + jb + wc * 64 + li * 4) = pk;
        }
}

// ---------------- sort helpers (256 threads) ----------------
__device__ inline void bitonicU64N(u64* a, int tid, int NE) {
    for (int ks = 2; ks <= NE; ks <<= 1)
        for (int js = ks >> 1; js > 0; js >>= 1) {
            __syncthreads();
            for (int e = tid; e < NE; e += 256) {
                int p = e ^ js;
                if (p > e) {
                    u64 A = a[e], B = a[p];
                    if ((A > B) == ((e & ks) == 0)) { a[e] = B; a[p] = A; }
                }
            }
        }
    __syncthreads();
}
__device__ inline void bitonicU16N(u16* a, int tid, int NE) {
    for (int ks = 2; ks <= NE; ks <<= 1)
        for (int js = ks >> 1; js > 0; js >>= 1) {
            __syncthreads();
            for (int e = tid; e < NE; e += 256) {
                int p = e ^ js;
                if (p > e) {
                    u16 A = a[e], B = a[p];
                    if ((A > B) == ((e & ks) == 0)) { a[e] = B; a[p] = A; }
                }
            }
        }
    __syncthreads();
}

// ---------------- K2: approx top-KSEL select + FUSED exact fp32 refine ----------
__global__ __launch_bounds__(256) void k2_select(const u16* __restrict__ distu, int row0,
                                                 const float* __restrict__ x,
                                                 const float* __restrict__ trainX,
                                                 const float* __restrict__ xx,
                                                 const float* __restrict__ tt,
                                                 int* __restrict__ nidx,
                                                 float* __restrict__ nsq) {
    const int tid = threadIdx.x;
    const int b = row0 + blockIdx.x;
    const u16* row = distu + (size_t)blockIdx.x * N_PAD;
    const uint4* row8 = (const uint4*)row;
    __shared__ u64 buf[CAP];            // 16 KB; overlaid by u16 sample array
    __shared__ int s_cnt;
    __shared__ int sIdx[KSEL];
    __shared__ float4 xs4[64];
    u16* samp = (u16*)buf;

    // sample positions 0..NSAMP-1 (1024 u16 = 128 uint4)
    if (tid < NSAMP / 8) ((uint4*)samp)[tid] = row8[tid];
    __syncthreads();
    bitonicU16N(samp, tid, NSAMP);
    int Tc = (int)samp[SRANK];
    __syncthreads();                    // samp dead; buf reuse

    int cnt = 0;
    for (int att = 0; att < 8; ++att) {
        if (tid == 0) s_cnt = 0;
        __syncthreads();
        for (int j8 = tid; j8 < N_PAD / 8; j8 += 256) {
            uint4 v = row8[j8];
            unsigned w_[4] = {v.x, v.y, v.z, v.w};
            #pragma unroll
            for (int c2 = 0; c2 < 4; ++c2) {
                #pragma unroll
                for (int hc = 0; hc < 2; ++hc) {
                    int code = (int)(hc ? (w_[c2] >> 16) : (w_[c2] & 0xFFFFu));
                    if (code < Tc) {
                        int p = atomicAdd(&s_cnt, 1);
                        if (p < CAP) buf[p] = ((u64)(unsigned)code << 32)
                                            | (unsigned)(j8 * 8 + c2 * 2 + hc);
                    }
                }
            }
        }
        __syncthreads();
        cnt = s_cnt;
        if (cnt >= KSEL && cnt <= CAP) break;
        Tc += (cnt < KSEL) ? 8 : -8;
        __syncthreads();
    }
    if (cnt > CAP) cnt = CAP;
    int NE = KSEL;                      // adaptive sort size (block-uniform)
    while (NE < cnt) NE <<= 1;          // <= CAP
    for (int i = tid; i < NE; i += 256) if (i >= cnt) buf[i] = ~0ull;
    __syncthreads();
    bitonicU64N(buf, tid, NE);
    {   // decode candidate col (invert k1m position perm)
        u64 e = buf[tid];
        int jraw = (e == ~0ull) ? 0 : (int)(e & 0xFFFFFFFFull);
        int base = (jraw >> 7) << 7, off = jraw & 127;
        sIdx[tid] = base + (off & 64) + ((off & 3) << 4) + ((off & 63) >> 2);
    }
    if (tid < 64) xs4[tid] = ((const float4*)(x + (size_t)b * D_DIM))[tid];
    __syncthreads();

    // fused exact fp32 refine: 32 lanes per candidate, keys reuse buf
    const int lane = tid & 63, wv = tid >> 6;
    const int ls = lane & 31;
    const float xxb = xx[b];
    for (int it = 0; it < KSEL / 8; ++it) {
        int c = it * 8 + wv * 2 + (lane >> 5);
        int j = sIdx[c];
        const float4* tr = (const float4*)(trainX + (size_t)j * D_DIM);
        float4 p1 = tr[ls * 2], p2 = tr[ls * 2 + 1];
        float4 q1 = xs4[ls * 2], q2 = xs4[ls * 2 + 1];
        float d = p1.x*q1.x + p1.y*q1.y + p1.z*q1.z + p1.w*q1.w
                + p2.x*q2.x + p2.y*q2.y + p2.z*q2.z + p2.w*q2.w;
        #pragma unroll
        for (int m = 1; m < 32; m <<= 1) d += __shfl_xor(d, m, 64);
        if (ls == 0) {
            float sq = fmaxf(xxb + tt[j] - 2.0f * d, 0.f);
            buf[c] = ((u64)__float_as_uint(sq) << 32) | (unsigned)j;
        }
    }
    __syncthreads();
    bitonicU64N(buf, tid, KSEL);
    if (tid < NN) {
        u64 e = buf[tid];
        nidx[(size_t)b * NN + tid] = (int)(e & 0xFFFFFFFFull);
        nsq[(size_t)b * NN + tid]  = __uint_as_float((unsigned)(e >> 32));
    }
}

// ---------------- K3: MFMA Gram + single-barrier rank-4 blocked LDL^T -----------
// (256,2), 64-elem/thread tile (bracketed optimum). NEW: forward publishes RAW
// pivot rows only; every thread inlines the 4-term Crout chain (6 FMA) on each
// panel float4 it reads -> phase B (barrier + serial tid<128 factor + LDS
// round-trip) eliminated. Publish for panel kb+1 overlapped at end of region kb
// (dbuf). Forward barriers 64 -> 33. Backward publish pipelined (static em).
__global__ __launch_bounds__(256, 2) void k3_solve(
    const u16* __restrict__ Bh, const u16* __restrict__ Bl,
    const float* __restrict__ trainy,
    const float* __restrict__ noise, const float* __restrict__ tt,
    const int* __restrict__ nidx, const float* __restrict__ nsq,
    const float* __restrict__ lp, const float* __restrict__ ap,
    const float* __restrict__ ymp, float* __restrict__ out) {

    __shared__ u16 Shi[128][40];
    __shared__ u16 Slo[128][40];
    __shared__ __align__(16) float pbufT[2][NN][4];  // [row][pivot-slot], dbuf
    __shared__ float diagb[2][4][4];    // raw 4x4 diagonal block, dbuf
    __shared__ float yLds[NN], yfwd[NN], dvec[NN], wvec[NN];
    __shared__ int   idxs[NN];
    __shared__ float ttn[NN], c0v[NN];
    __shared__ float red[8];

    const int b = blockIdx.x;
    const int tid = threadIdx.x;
    const int lane = tid & 63, wv = tid >> 6;
    const int wr = wv >> 1, wc = wv & 1;
    const int lr = lane & 15, lq = lane >> 4;   // C-layout: col-lane, row-quad

    const float lv = expf(lp[0]);
    const float av = expf(ap[0]);
    const float ymean = ymp[0];
    const float sc = 1.0f / (lv * 16.0f);   // sqrt(D)=16

    if (tid < NN) {
        int ix = nidx[(size_t)b * NN + tid];
        idxs[tid] = ix;
        ttn[tid] = tt[ix];
        float cc = av * expf(-sqrtf(nsq[(size_t)b * NN + tid]) * sc);
        c0v[tid] = cc;
        yLds[tid] = cc;                 // rhs
    }
    __syncthreads();

    f32x4 acc[4][4];
    #pragma unroll
    for (int m = 0; m < 4; ++m)
        #pragma unroll
        for (int n = 0; n < 4; ++n)
            #pragma unroll
            for (int r = 0; r < 4; ++r) acc[m][n][r] = 0.f;

    for (int c = 0; c < 8; ++c) {       // 8 chunks of 32 dims, gathered pre-split
        #pragma unroll
        for (int s = 0; s < 2; ++s) {
            int idx = tid + s * 256;    // 0..511 = 128 rows x 4 uint4
            int row = idx >> 2, kp = (idx & 3) << 3;
            size_t base = (size_t)idxs[row] * D_DIM + c * 32 + kp;
            *(uint4*)&Shi[row][kp] = *(const uint4*)(Bh + base);
            *(uint4*)&Slo[row][kp] = *(const uint4*)(Bl + base);
        }
        __syncthreads();
        {
            short8v ahi[4], bhi[4];
            #pragma unroll
            for (int m = 0; m < 4; ++m)
                ahi[m] = *(const short8v*)&Shi[wr * 64 + m * 16 + lr][lq * 8];
            #pragma unroll
            for (int n = 0; n < 4; ++n)
                bhi[n] = *(const short8v*)&Shi[wc * 64 + n * 16 + lr][lq * 8];
            #pragma unroll
            for (int m = 0; m < 4; ++m)
                #pragma unroll
                for (int n = 0; n < 4; ++n)
                    acc[m][n] = __builtin_amdgcn_mfma_f32_16x16x32_bf16(ahi[m], bhi[n], acc[m][n], 0, 0, 0);
            #pragma unroll
            for (int n = 0; n < 4; ++n) {           // b-lo pass, 1 frag live
                short8v blo = *(const short8v*)&Slo[wc * 64 + n * 16 + lr][lq * 8];
                #pragma unroll
                for (int m = 0; m < 4; ++m)
                    acc[m][n] = __builtin_amdgcn_mfma_f32_16x16x32_bf16(ahi[m], blo, acc[m][n], 0, 0, 0);
            }
            #pragma unroll
            for (int m = 0; m < 4; ++m) {           // a-lo pass, 1 frag live
                short8v alo = *(const short8v*)&Slo[wr * 64 + m * 16 + lr][lq * 8];
                #pragma unroll
                for (int n = 0; n < 4; ++n)
                    acc[m][n] = __builtin_amdgcn_mfma_f32_16x16x32_bf16(alo, bhi[n], acc[m][n], 0, 0, 0);
            }
        }
        __syncthreads();
    }

    // transform acc -> VGPR-resident kernel matrix em (acc/AGPRs die here)
    float em[4][4][4];
    #pragma unroll
    for (int m = 0; m < 4; ++m) {
        #pragma unroll
        for (int r = 0; r < 4; ++r) {
            int i = wr * 64 + m * 16 + lq * 4 + r;
            float ti = ttn[i];
            #pragma unroll
            for (int n = 0; n < 4; ++n) {
                int j = wc * 64 + n * 16 + lr;
                float sq = fmaxf(ti + ttn[j] - 2.0f * acc[m][n][r], 0.0f);
                em[m][n][r] = av * expf(-sqrtf(sq) * sc);
            }
        }
    }

    // owner publish of raw pivot rows for panel kb2 (writes pbufT/diagb[kb2&1])
    auto publishPanel = [&](int kb2) {
        const int k0p = kb2 * 4;
        const int parp = kb2 & 1;
        if (wr == (k0p >> 6) && lq == ((k0p & 15) >> 2)) {
            #pragma unroll
            for (int mm = 0; mm < 4; ++mm)
                if (mm == ((k0p >> 4) & 3)) {
                    #pragma unroll
                    for (int n = 0; n < 4; ++n) {
                        int j = wc * 64 + n * 16 + lr;
                        *(float4*)&pbufT[parp][j][0] =
                            make_float4(em[mm][n][0], em[mm][n][1], em[mm][n][2], em[mm][n][3]);
                        int cd = j - k0p;
                        if (cd >= 0 && cd < 4) {
                            #pragma unroll
                            for (int r = 0; r < 4; ++r)
                                diagb[parp][r][cd] = em[mm][n][r];
                        }
                    }
                }
        }
    };
    // owner publish of FACTORED columns (em is static during backward)
    auto publishCols = [&](int kb2) {
        const int k0p = kb2 * 4;
        const int parp = kb2 & 1;
        int q = lr - (k0p & 15);
        if (wc == (k0p >> 6) && q >= 0 && q < 4) {
            #pragma unroll
            for (int nn = 0; nn < 4; ++nn)
                if (nn == ((k0p >> 4) & 3)) {
                    #pragma unroll
                    for (int m = 0; m < 4; ++m)
                        #pragma unroll
                        for (int r = 0; r < 4; ++r)
                            pbufT[parp][wr * 64 + m * 16 + lq * 4 + r][q] = em[m][nn][r];
                }
        }
    };

    // ---- forward rank-4 blocked LDL^T, SINGLE barrier per 4 pivots ----
    publishPanel(0);
    for (int kb = 0; kb < 32; ++kb) {
        const int k0 = kb * 4;
        const int par = kb & 1;
        __syncthreads();
        // uniform Crout scalars from the raw diag block
        float d0 = diagb[par][0][0], i0 = 1.0f / d0;
        float B01 = diagb[par][0][1], B02 = diagb[par][0][2], B03 = diagb[par][0][3];
        float l10 = diagb[par][1][0] * i0;
        float l20 = diagb[par][2][0] * i0;
        float l30 = diagb[par][3][0] * i0;
        float d1 = diagb[par][1][1] - l10 * B01, i1 = 1.0f / d1;
        float t12 = diagb[par][1][2] - l10 * B02;
        float t13 = diagb[par][1][3] - l10 * B03;
        float l21 = (diagb[par][2][1] - l20 * B01) * i1;
        float l31 = (diagb[par][3][1] - l30 * B01) * i1;
        float d2 = diagb[par][2][2] - l20 * B02 - l21 * t12, i2 = 1.0f / d2;
        float t23 = diagb[par][2][3] - l20 * B03 - l21 * t13;
        float l32 = (diagb[par][3][2] - l30 * B02 - l31 * t12) * i2;
        float d3 = diagb[par][3][3] - l30 * B03 - l31 * t13 - l32 * t23, i3 = 1.0f / d3;
        // column chains: factor raw cj values in registers
        float cj0[4], cj1[4], cj2[4], cj3[4];
        #pragma unroll
        for (int n = 0; n < 4; ++n) {
            int j = wc * 64 + n * 16 + lr;
            float4 cv = *(const float4*)&pbufT[par][j][0];
            float a0 = cv.x;
            float a1 = cv.y - l10 * a0;
            float a2 = cv.z - l20 * a0 - l21 * a1;
            float a3 = cv.w - l30 * a0 - l31 * a1 - l32 * a2;
            cj0[n] = (j > k0)     ? a0 : 0.f;
            cj1[n] = (j > k0 + 1) ? a1 : 0.f;
            cj2[n] = (j > k0 + 2) ? a2 : 0.f;
            cj3[n] = (j > k0 + 3) ? a3 : 0.f;
        }
        // row chains + rank-4 register update
        #pragma unroll
        for (int m = 0; m < 4; ++m)
            #pragma unroll
            for (int rr = 0; rr < 4; ++rr) {
                int i = wr * 64 + m * 16 + lq * 4 + rr;
                float4 rv = *(const float4*)&pbufT[par][i][0];   // broadcast in wave
                float b0 = rv.x;
                float b1 = rv.y - l10 * b0;
                float b2 = rv.z - l20 * b0 - l21 * b1;
                float b3 = rv.w - l30 * b0 - l31 * b1 - l32 * b2;
                float k0v = (i > k0)     ? b0 * i0 : 0.f;
                float k1v = (i > k0 + 1) ? b1 * i1 : 0.f;
                float k2v = (i > k0 + 2) ? b2 * i2 : 0.f;
                float k3v = (i > k0 + 3) ? b3 * i3 : 0.f;
                #pragma unroll
                for (int n = 0; n < 4; ++n) {
                    float t = em[m][n][rr];
                    t = fmaf(-k0v, cj0[n], t);
                    t = fmaf(-k1v, cj1[n], t);
                    t = fmaf(-k2v, cj2[n], t);
                    t = fmaf(-k3v, cj3[n], t);
                    em[m][n][rr] = t;
                }
            }
        // rhs forward (8 owner lanes) + dvec/yfwd (tid 0)
        if (wc == 0 && lr == 0) {
            float fy0 = yLds[k0];
            float fy1 = yLds[k0+1] - l10 * fy0;
            float fy2 = yLds[k0+2] - l20 * fy0 - l21 * fy1;
            float fy3 = yLds[k0+3] - l30 * fy0 - l31 * fy1 - l32 * fy2;
            #pragma unroll
            for (int m = 0; m < 4; ++m)
                #pragma unroll
                for (int rr = 0; rr < 4; ++rr) {
                    int i = wr * 64 + m * 16 + lq * 4 + rr;
                    if (i > k0 + 3) {
                        float4 rv = *(const float4*)&pbufT[par][i][0];
                        float b0 = rv.x;
                        float b1 = rv.y - l10 * b0;
                        float b2 = rv.z - l20 * b0 - l21 * b1;
                        float b3 = rv.w - l30 * b0 - l31 * b1 - l32 * b2;
                        float yv = yLds[i];
                        yv = fmaf(-b0 * i0, fy0, yv);
                        yv = fmaf(-b1 * i1, fy1, yv);
                        yv = fmaf(-b2 * i2, fy2, yv);
                        yv = fmaf(-b3 * i3, fy3, yv);
                        yLds[i] = yv;
                    }
                }
            if (tid == 0) {
                dvec[k0] = d0; dvec[k0+1] = d1; dvec[k0+2] = d2; dvec[k0+3] = d3;
                yfwd[k0] = fy0; yfwd[k0+1] = fy1; yfwd[k0+2] = fy2; yfwd[k0+3] = fy3;
            }
        }
        if (kb < 31) publishPanel(kb + 1);   // overlapped publish (other dbuf half)
    }
    __syncthreads();
    if (tid < NN) yLds[tid] = yfwd[tid];     // consolidated forward-solved rhs
    __syncthreads();

    // ---- backward rank-4 (1 barrier per 4 pivots, publish pipelined) ----
    publishCols(31);
    for (int kb = 31; kb >= 0; --kb) {
        const int k0 = kb * 4;
        const int par = kb & 1;
        __syncthreads();
        if (kb > 0) publishCols(kb - 1);     // static em, other dbuf half
        float w3 = yLds[k0+3] / dvec[k0+3];
        float w2 = (yLds[k0+2] - pbufT[par][k0+2][3] * w3) / dvec[k0+2];
        float w1 = (yLds[k0+1] - pbufT[par][k0+1][2] * w2 - pbufT[par][k0+1][3] * w3) / dvec[k0+1];
        float w0 = (yLds[k0]   - pbufT[par][k0][1] * w1 - pbufT[par][k0][2] * w2
                               - pbufT[par][k0][3] * w3) / dvec[k0];
        if (tid == 0) { wvec[k0] = w0; wvec[k0+1] = w1; wvec[k0+2] = w2; wvec[k0+3] = w3; }
        if (tid < k0) {
            float4 pv = *(const float4*)&pbufT[par][tid][0];   // one b128 per thread
            float yv = yLds[tid];
            yv = fmaf(-pv.x, w0, yv);
            yv = fmaf(-pv.y, w1, yv);
            yv = fmaf(-pv.z, w2, yv);
            yv = fmaf(-pv.w, w3, yv);
            yLds[tid] = yv;
        }
    }
    __syncthreads();

    float p1 = 0.f, p2 = 0.f;
    if (tid < NN) {
        float w = wvec[tid];
        float nyv = trainy[idxs[tid]] + 0.01f * noise[(size_t)b * NN + tid] - ymean;
        p1 = w * nyv;
        p2 = w * c0v[tid];
    }
    for (int off = 32; off; off >>= 1) {
        p1 += __shfl_down(p1, off, 64);
        p2 += __shfl_down(p2, off, 64);
    }
    if ((tid & 63) == 0) { red[wv * 2] = p1; red[wv * 2 + 1] = p2; }
    __syncthreads();
    if (tid == 0) {
        out[b]        = (red[0] + red[2] + red[4] + red[6]) + ymean;
        out[B_SZ + b] = av - (red[1] + red[3] + red[5] + red[7]);
    }
}

extern "C" void kernel_launch(void* const* d_in, const int* in_sizes, int n_in,
                              void* d_out, int out_size, void* d_ws, size_t ws_size,
                              hipStream_t stream) {
    const float* x      = (const float*)d_in[0];
    const float* trainX = (const float*)d_in[1];
    const float* trainy = (const float*)d_in[2];
    const float* noise  = (const float*)d_in[3];
    const float* lp     = (const float*)d_in[4];
    const float* ap     = (const float*)d_in[5];
    const float* ymp    = (const float*)d_in[6];
    float* out = (float*)d_out;

    char* ws = (char*)d_ws;
    size_t off = 0;
    auto alloc = [&](size_t bytes) {
        void* p = ws + off;
        off = (off + bytes + 255) & ~(size_t)255;
        return p;
    };
    float* tt   = (float*)alloc((size_t)N_TRAIN * 4);
    float* xx   = (float*)alloc((size_t)B_SZ * 4);
    int*   nidb = (int*)  alloc((size_t)B_SZ * NN * 4);
    float* nsqb = (float*)alloc((size_t)B_SZ * NN * 4);
    u16*   Ah   = (u16*)  alloc((size_t)B_SZ * D_DIM * 2);
    u16*   Bh   = (u16*)  alloc((size_t)N_TRAIN * D_DIM * 2);
    u16*   Bl   = (u16*)  alloc((size_t)N_TRAIN * D_DIM * 2);
    size_t distBytes = (ws_size > off) ? (ws_size - off) : 0;
    u16* distu = (u16*)(ws + off);
    int R = (int)(distBytes / ((size_t)N_PAD * 2));
    if (R > B_SZ) R = B_SZ;      // single chunk if ws allows (k2 occupancy 4/CU)
    if (R < 1) R = 1;

    {
        int waves = N_TRAIN + B_SZ;
        kprep<<<(waves + 3) / 4, 256, 0, stream>>>(trainX, x, tt, xx, Bh, Bl, Ah);
    }

    for (int r0 = 0; r0 < B_SZ; r0 += R) {
        int rc = (B_SZ - r0 < R) ? (B_SZ - r0) : R;
        dim3 g1((N_TRAIN + 127) / 128, (rc + 127) / 128);
        k1m<<<g1, 256, 0, stream>>>(Ah, Bh, xx, tt, distu, r0, rc);
        k2_select<<<rc, 256, 0, stream>>>(distu, r0, x, trainX, xx, tt, nidb, nsqb);
    }
    k3_solve<<<B_SZ, 256, 0, stream>>>(Bh, Bl, trainy, noise, tt, nidb, nsqb,
                                       lp, ap, ymp, out);
}

// Round 20
// 627.563 us; speedup vs baseline: 1.2727x; 1.2727x over previous
//
#include <hip/hip_runtime.h>
#include <math.h>
#include <stdint.h>

#define B_SZ    1024
#define N_TRAIN 100000
#define N_PAD   100096       // 782 tiles * 128 (permuted-position row stride)
#define D_DIM   256
#define NN      128
#define KSEL    256          // candidate count (margin 128 ranks over 128)
#define CAP     2048         // k2 collect buffer
#define NSAMP   1024         // k2 sample count
#define SRANK   8            // k2 sample threshold rank (of NSAMP) -> E[cnt]~780

typedef unsigned short u16;
typedef unsigned long long u64;
typedef __attribute__((ext_vector_type(8))) short short8v;
typedef __attribute__((ext_vector_type(4))) float f32x4;

__device__ inline u16 f2bf(float f) {
    unsigned u = __float_as_uint(f);
    return (u16)((u + 0x7FFFu + ((u >> 16) & 1u)) >> 16);
}
__device__ inline float bf2f(u16 h) { return __uint_as_float((unsigned)h << 16); }

// ---------------- Kprep: fused norms + bf16 hi/lo split (one pass over inputs) --
__global__ __launch_bounds__(256) void kprep(const float* __restrict__ trainX,
                                             const float* __restrict__ x,
                                             float* __restrict__ tt,
                                             float* __restrict__ xx,
                                             u16* __restrict__ Bh,
                                             u16* __restrict__ Bl,
                                             u16* __restrict__ Ah) {
    int wave = (blockIdx.x * blockDim.x + threadIdx.x) >> 6;
    int lane = threadIdx.x & 63;
    if (wave >= N_TRAIN + B_SZ) return;
    const bool isTrain = wave < N_TRAIN;
    const float* row = isTrain ? (trainX + (size_t)wave * D_DIM)
                               : (x + (size_t)(wave - N_TRAIN) * D_DIM);
    float4 v = ((const float4*)row)[lane];
    float s = v.x*v.x + v.y*v.y + v.z*v.z + v.w*v.w;
    for (int off = 32; off; off >>= 1) s += __shfl_down(s, off, 64);
    u16 h0 = f2bf(v.x), h1 = f2bf(v.y), h2 = f2bf(v.z), h3 = f2bf(v.w);
    u64 hp = (u64)h0 | ((u64)h1 << 16) | ((u64)h2 << 32) | ((u64)h3 << 48);
    if (isTrain) {
        ((u64*)(Bh + (size_t)wave * D_DIM))[lane] = hp;
        u16 l0 = f2bf(v.x - bf2f(h0)), l1 = f2bf(v.y - bf2f(h1));
        u16 l2 = f2bf(v.z - bf2f(h2)), l3 = f2bf(v.w - bf2f(h3));
        ((u64*)(Bl + (size_t)wave * D_DIM))[lane] =
            (u64)l0 | ((u64)l1 << 16) | ((u64)l2 << 32) | ((u64)l3 << 48);
        if (lane == 0) tt[wave] = s;
    } else {
        ((u64*)(Ah + (size_t)(wave - N_TRAIN) * D_DIM))[lane] = hp;
        if (lane == 0) xx[wave - N_TRAIN] = s;
    }
}

// ---------------- K1m: bf16 MFMA GEMM -> approx sq distances (u16, permuted) ----
__global__ __launch_bounds__(256) void k1m(const u16* __restrict__ Ah,
                                           const u16* __restrict__ Bh,
                                           const float* __restrict__ xx,
                                           const float* __restrict__ tt,
                                           u16* __restrict__ distu,
                                           int row0, int nrows) {
    __shared__ u16 Als[4][128][8];    // [kslot][row][8 bf16] -> 16B chunks
    __shared__ u16 Bls[4][128][8];
    const int tid = threadIdx.x;
    const int lane = tid & 63, wv = tid >> 6;
    const int wr = wv >> 1, wc = wv & 1;
    const int ib = blockIdx.y * 128;
    const size_t jb = (size_t)blockIdx.x * 128;

    f32x4 acc[4][4];
    #pragma unroll
    for (int m = 0; m < 4; ++m)
        #pragma unroll
        for (int n = 0; n < 4; ++n)
            #pragma unroll
            for (int r = 0; r < 4; ++r) acc[m][n][r] = 0.f;

    for (int k0 = 0; k0 < D_DIM; k0 += 32) {
        #pragma unroll
        for (int r = 0; r < 2; ++r) {
            int c = tid + r * 256;            // 0..511
            int row = c >> 2, ks = c & 3;
            uint4 va = make_uint4(0, 0, 0, 0);
            if (ib + row < nrows)
                va = *(const uint4*)(Ah + (size_t)(row0 + ib + row) * D_DIM + k0 + ks * 8);
            *(uint4*)(&Als[ks][row][0]) = va;
            uint4 vb = make_uint4(0, 0, 0, 0);
            if (jb + row < N_TRAIN)
                vb = *(const uint4*)(Bh + (jb + row) * D_DIM + k0 + ks * 8);
            *(uint4*)(&Bls[ks][row][0]) = vb;
        }
        __syncthreads();
        const int ksl = lane >> 4, li = lane & 15;
        short8v a[4], b[4];
        #pragma unroll
        for (int m = 0; m < 4; ++m)
            a[m] = *(const short8v*)&Als[ksl][wr * 64 + m * 16 + li][0];
        #pragma unroll
        for (int n = 0; n < 4; ++n)
            b[n] = *(const short8v*)&Bls[ksl][wc * 64 + n * 16 + li][0];
        #pragma unroll
        for (int m = 0; m < 4; ++m)
            #pragma unroll
            for (int n = 0; n < 4; ++n)
                acc[m][n] = __builtin_amdgcn_mfma_f32_16x16x32_bf16(a[m], b[n], acc[m][n], 0, 0, 0);
        __syncthreads();
    }
    // epilogue: C row = (lane>>4)*4 + reg, col = lane&15; packed u64 permuted store
    const int li = lane & 15, lh = lane >> 4;
    float ttv[4]; int cols[4];
    #pragma unroll
    for (int n = 0; n < 4; ++n) {
        cols[n] = (int)jb + wc * 64 + n * 16 + li;
        ttv[n] = (cols[n] < N_TRAIN) ? tt[cols[n]] : 0.f;
    }
    #pragma unroll
    for (int m = 0; m < 4; ++m)
        #pragma unroll
        for (int r = 0; r < 4; ++r) {
            int rl = ib + wr * 64 + m * 16 + lh * 4 + r;
            if (rl >= nrows) continue;
            float xi = xx[row0 + rl];
            u64 pk = 0;
            #pragma unroll
            for (int n = 0; n < 4; ++n) {
                u16 code = 0xFFFFu;
                if (cols[n] < N_TRAIN)
                    code = f2bf(fmaxf(xi + ttv[n] - 2.0f * acc[m][n][r], 0.f));
                pk |= (u64)code << (16 * n);
            }
            *(u64*)(distu + (size_t)rl * N_PAD + jb + wc * 64 + li * 4) = pk;
        }
}

// ---------------- sort helpers (256 threads) ----------------
__device__ inline void bitonicU64N(u64* a, int tid, int NE) {
    for (int ks = 2; ks <= NE; ks <<= 1)
        for (int js = ks >> 1; js > 0; js >>= 1) {
            __syncthreads();
            for (int e = tid; e < NE; e += 256) {
                int p = e ^ js;
                if (p > e) {
                    u64 A = a[e], B = a[p];
                    if ((A > B) == ((e & ks) == 0)) { a[e] = B; a[p] = A; }
                }
            }
        }
    __syncthreads();
}
__device__ inline void bitonicU16N(u16* a, int tid, int NE) {
    for (int ks = 2; ks <= NE; ks <<= 1)
        for (int js = ks >> 1; js > 0; js >>= 1) {
            __syncthreads();
            for (int e = tid; e < NE; e += 256) {
                int p = e ^ js;
                if (p > e) {
                    u16 A = a[e], B = a[p];
                    if ((A > B) == ((e & ks) == 0)) { a[e] = B; a[p] = A; }
                }
            }
        }
    __syncthreads();
}

// ---------------- K2: approx top-KSEL select + FUSED exact fp32 refine ----------
__global__ __launch_bounds__(256) void k2_select(const u16* __restrict__ distu, int row0,
                                                 const float* __restrict__ x,
                                                 const float* __restrict__ trainX,
                                                 const float* __restrict__ xx,
                                                 const float* __restrict__ tt,
                                                 int* __restrict__ nidx,
                                                 float* __restrict__ nsq) {
    const int tid = threadIdx.x;
    const int b = row0 + blockIdx.x;
    const u16* row = distu + (size_t)blockIdx.x * N_PAD;
    const uint4* row8 = (const uint4*)row;
    __shared__ u64 buf[CAP];            // 16 KB; overlaid by u16 sample array
    __shared__ int s_cnt;
    __shared__ int sIdx[KSEL];
    __shared__ float4 xs4[64];
    u16* samp = (u16*)buf;

    // sample positions 0..NSAMP-1 (1024 u16 = 128 uint4)
    if (tid < NSAMP / 8) ((uint4*)samp)[tid] = row8[tid];
    __syncthreads();
    bitonicU16N(samp, tid, NSAMP);
    int Tc = (int)samp[SRANK];
    __syncthreads();                    // samp dead; buf reuse

    int cnt = 0;
    for (int att = 0; att < 8; ++att) {
        if (tid == 0) s_cnt = 0;
        __syncthreads();
        for (int j8 = tid; j8 < N_PAD / 8; j8 += 256) {
            uint4 v = row8[j8];
            unsigned w_[4] = {v.x, v.y, v.z, v.w};
            #pragma unroll
            for (int c2 = 0; c2 < 4; ++c2) {
                #pragma unroll
                for (int hc = 0; hc < 2; ++hc) {
                    int code = (int)(hc ? (w_[c2] >> 16) : (w_[c2] & 0xFFFFu));
                    if (code < Tc) {
                        int p = atomicAdd(&s_cnt, 1);
                        if (p < CAP) buf[p] = ((u64)(unsigned)code << 32)
                                            | (unsigned)(j8 * 8 + c2 * 2 + hc);
                    }
                }
            }
        }
        __syncthreads();
        cnt = s_cnt;
        if (cnt >= KSEL && cnt <= CAP) break;
        Tc += (cnt < KSEL) ? 8 : -8;
        __syncthreads();
    }
    if (cnt > CAP) cnt = CAP;
    int NE = KSEL;                      // adaptive sort size (block-uniform)
    while (NE < cnt) NE <<= 1;          // <= CAP
    for (int i = tid; i < NE; i += 256) if (i >= cnt) buf[i] = ~0ull;
    __syncthreads();
    bitonicU64N(buf, tid, NE);
    {   // decode candidate col (invert k1m position perm)
        u64 e = buf[tid];
        int jraw = (e == ~0ull) ? 0 : (int)(e & 0xFFFFFFFFull);
        int base = (jraw >> 7) << 7, off = jraw & 127;
        sIdx[tid] = base + (off & 64) + ((off & 3) << 4) + ((off & 63) >> 2);
    }
    if (tid < 64) xs4[tid] = ((const float4*)(x + (size_t)b * D_DIM))[tid];
    __syncthreads();

    // fused exact fp32 refine: 32 lanes per candidate, keys reuse buf
    const int lane = tid & 63, wv = tid >> 6;
    const int ls = lane & 31;
    const float xxb = xx[b];
    for (int it = 0; it < KSEL / 8; ++it) {
        int c = it * 8 + wv * 2 + (lane >> 5);
        int j = sIdx[c];
        const float4* tr = (const float4*)(trainX + (size_t)j * D_DIM);
        float4 p1 = tr[ls * 2], p2 = tr[ls * 2 + 1];
        float4 q1 = xs4[ls * 2], q2 = xs4[ls * 2 + 1];
        float d = p1.x*q1.x + p1.y*q1.y + p1.z*q1.z + p1.w*q1.w
                + p2.x*q2.x + p2.y*q2.y + p2.z*q2.z + p2.w*q2.w;
        #pragma unroll
        for (int m = 1; m < 32; m <<= 1) d += __shfl_xor(d, m, 64);
        if (ls == 0) {
            float sq = fmaxf(xxb + tt[j] - 2.0f * d, 0.f);
            buf[c] = ((u64)__float_as_uint(sq) << 32) | (unsigned)j;
        }
    }
    __syncthreads();
    bitonicU64N(buf, tid, KSEL);
    if (tid < NN) {
        u64 e = buf[tid];
        nidx[(size_t)b * NN + tid] = (int)(e & 0xFFFFFFFFull);
        nsq[(size_t)b * NN + tid]  = __uint_as_float((unsigned)(e >> 32));
    }
}

// ---------------- K3: MFMA Gram + rank-4 blocked LDL^T, float4 panel buffer -----
// (256,2) with the 64-elem/thread tile is k3's bracketed optimum: (256,4),
// (256,3), rank-8, 512-thread/(512,4), and single-barrier-inline (R19) all
// spill or dilute. pbufT [row][4] makes publish/factor/phase-C/backward all
// single-b128 LDS ops. This exact version measured 267us (R16/R18).
__global__ __launch_bounds__(256, 2) void k3_solve(
    const u16* __restrict__ Bh, const u16* __restrict__ Bl,
    const float* __restrict__ trainy,
    const float* __restrict__ noise, const float* __restrict__ tt,
    const int* __restrict__ nidx, const float* __restrict__ nsq,
    const float* __restrict__ lp, const float* __restrict__ ap,
    const float* __restrict__ ymp, float* __restrict__ out) {

    __shared__ u16 Shi[128][40];
    __shared__ u16 Slo[128][40];
    __shared__ __align__(16) float pbufT[2][NN][4];  // [row][pivot-slot], dbuf
    __shared__ float diagb[2][4][4];    // raw 4x4 diagonal block, dbuf
    __shared__ float yLds[NN], yfwd[NN], dvec[NN], wvec[NN];
    __shared__ int   idxs[NN];
    __shared__ float ttn[NN], c0v[NN];
    __shared__ float red[8];

    const int b = blockIdx.x;
    const int tid = threadIdx.x;
    const int lane = tid & 63, wv = tid >> 6;
    const int wr = wv >> 1, wc = wv & 1;
    const int lr = lane & 15, lq = lane >> 4;   // C-layout: col-lane, row-quad

    const float lv = expf(lp[0]);
    const float av = expf(ap[0]);
    const float ymean = ymp[0];
    const float sc = 1.0f / (lv * 16.0f);   // sqrt(D)=16

    if (tid < NN) {
        int ix = nidx[(size_t)b * NN + tid];
        idxs[tid] = ix;
        ttn[tid] = tt[ix];
        float cc = av * expf(-sqrtf(nsq[(size_t)b * NN + tid]) * sc);
        c0v[tid] = cc;
        yLds[tid] = cc;                 // rhs
    }
    __syncthreads();

    f32x4 acc[4][4];
    #pragma unroll
    for (int m = 0; m < 4; ++m)
        #pragma unroll
        for (int n = 0; n < 4; ++n)
            #pragma unroll
            for (int r = 0; r < 4; ++r) acc[m][n][r] = 0.f;

    for (int c = 0; c < 8; ++c) {       // 8 chunks of 32 dims, gathered pre-split
        #pragma unroll
        for (int s = 0; s < 2; ++s) {
            int idx = tid + s * 256;    // 0..511 = 128 rows x 4 uint4
            int row = idx >> 2, kp = (idx & 3) << 3;
            size_t base = (size_t)idxs[row] * D_DIM + c * 32 + kp;
            *(uint4*)&Shi[row][kp] = *(const uint4*)(Bh + base);
            *(uint4*)&Slo[row][kp] = *(const uint4*)(Bl + base);
        }
        __syncthreads();
        {
            short8v ahi[4], bhi[4];
            #pragma unroll
            for (int m = 0; m < 4; ++m)
                ahi[m] = *(const short8v*)&Shi[wr * 64 + m * 16 + lr][lq * 8];
            #pragma unroll
            for (int n = 0; n < 4; ++n)
                bhi[n] = *(const short8v*)&Shi[wc * 64 + n * 16 + lr][lq * 8];
            #pragma unroll
            for (int m = 0; m < 4; ++m)
                #pragma unroll
                for (int n = 0; n < 4; ++n)
                    acc[m][n] = __builtin_amdgcn_mfma_f32_16x16x32_bf16(ahi[m], bhi[n], acc[m][n], 0, 0, 0);
            #pragma unroll
            for (int n = 0; n < 4; ++n) {           // b-lo pass, 1 frag live
                short8v blo = *(const short8v*)&Slo[wc * 64 + n * 16 + lr][lq * 8];
                #pragma unroll
                for (int m = 0; m < 4; ++m)
                    acc[m][n] = __builtin_amdgcn_mfma_f32_16x16x32_bf16(ahi[m], blo, acc[m][n], 0, 0, 0);
            }
            #pragma unroll
            for (int m = 0; m < 4; ++m) {           // a-lo pass, 1 frag live
                short8v alo = *(const short8v*)&Slo[wr * 64 + m * 16 + lr][lq * 8];
                #pragma unroll
                for (int n = 0; n < 4; ++n)
                    acc[m][n] = __builtin_amdgcn_mfma_f32_16x16x32_bf16(alo, bhi[n], acc[m][n], 0, 0, 0);
            }
        }
        __syncthreads();
    }

    // transform acc -> VGPR-resident kernel matrix em (acc/AGPRs die here)
    float em[4][4][4];
    #pragma unroll
    for (int m = 0; m < 4; ++m) {
        #pragma unroll
        for (int r = 0; r < 4; ++r) {
            int i = wr * 64 + m * 16 + lq * 4 + r;
            float ti = ttn[i];
            #pragma unroll
            for (int n = 0; n < 4; ++n) {
                int j = wc * 64 + n * 16 + lr;
                float sq = fmaxf(ti + ttn[j] - 2.0f * acc[m][n][r], 0.0f);
                em[m][n][r] = av * expf(-sqrtf(sq) * sc);
            }
        }
    }

    // ---- forward rank-4 blocked LDL^T, 3-phase (2 barriers per 4 pivots) ----
    for (int kb = 0; kb < 32; ++kb) {
        const int k0 = kb * 4;
        const int par = kb & 1;
        // Phase A: owners publish raw rows (b128 per column) + diag block
        if (wr == (k0 >> 6) && lq == ((k0 & 15) >> 2)) {
            #pragma unroll
            for (int mm = 0; mm < 4; ++mm)
                if (mm == ((k0 >> 4) & 3)) {
                    #pragma unroll
                    for (int n = 0; n < 4; ++n) {
                        int j = wc * 64 + n * 16 + lr;
                        *(float4*)&pbufT[par][j][0] =
                            make_float4(em[mm][n][0], em[mm][n][1], em[mm][n][2], em[mm][n][3]);
                        int cd = j - k0;
                        if (cd >= 0 && cd < 4) {
                            #pragma unroll
                            for (int r = 0; r < 4; ++r)
                                diagb[par][r][cd] = em[mm][n][r];
                        }
                    }
                }
        }
        __syncthreads();
        // Phase B: uniform Crout scalars (from diagb) + factor panel in LDS (b128)
        float d0 = diagb[par][0][0], i0 = 1.0f / d0;
        float B01 = diagb[par][0][1], B02 = diagb[par][0][2], B03 = diagb[par][0][3];
        float l10 = diagb[par][1][0] * i0;
        float l20 = diagb[par][2][0] * i0;
        float l30 = diagb[par][3][0] * i0;
        float d1 = diagb[par][1][1] - l10 * B01, i1 = 1.0f / d1;
        float t12 = diagb[par][1][2] - l10 * B02;
        float t13 = diagb[par][1][3] - l10 * B03;
        float l21 = (diagb[par][2][1] - l20 * B01) * i1;
        float l31 = (diagb[par][3][1] - l30 * B01) * i1;
        float d2 = diagb[par][2][2] - l20 * B02 - l21 * t12, i2 = 1.0f / d2;
        float t23 = diagb[par][2][3] - l20 * B03 - l21 * t13;
        float l32 = (diagb[par][3][2] - l30 * B02 - l31 * t12) * i2;
        float d3 = diagb[par][3][3] - l30 * B03 - l31 * t13 - l32 * t23, i3 = 1.0f / d3;
        if (tid < 128) {                // factor column tid of the 4-row panel
            float4 a = *(const float4*)&pbufT[par][tid][0];
            float a1 = a.y - l10 * a.x;
            float a2 = a.z - l20 * a.x - l21 * a1;
            float a3 = a.w - l30 * a.x - l31 * a1 - l32 * a2;
            a.y = a1; a.z = a2; a.w = a3;
            *(float4*)&pbufT[par][tid][0] = a;
        }
        __syncthreads();
        // Phase C: rank-4 register update; all LDS reads are b128
        float cj0[4], cj1[4], cj2[4], cj3[4];
        #pragma unroll
        for (int n = 0; n < 4; ++n) {
            int j = wc * 64 + n * 16 + lr;
            float4 cv = *(const float4*)&pbufT[par][j][0];
            cj0[n] = (j > k0)     ? cv.x : 0.f;
            cj1[n] = (j > k0 + 1) ? cv.y : 0.f;
            cj2[n] = (j > k0 + 2) ? cv.z : 0.f;
            cj3[n] = (j > k0 + 3) ? cv.w : 0.f;
        }
        #pragma unroll
        for (int m = 0; m < 4; ++m)
            #pragma unroll
            for (int rr = 0; rr < 4; ++rr) {
                int i = wr * 64 + m * 16 + lq * 4 + rr;
                float4 rv = *(const float4*)&pbufT[par][i][0];   // broadcast in wave
                float k0v = (i > k0)     ? rv.x * i0 : 0.f;
                float k1v = (i > k0 + 1) ? rv.y * i1 : 0.f;
                float k2v = (i > k0 + 2) ? rv.z * i2 : 0.f;
                float k3v = (i > k0 + 3) ? rv.w * i3 : 0.f;
                #pragma unroll
                for (int n = 0; n < 4; ++n) {
                    float t = em[m][n][rr];
                    t = fmaf(-k0v, cj0[n], t);
                    t = fmaf(-k1v, cj1[n], t);
                    t = fmaf(-k2v, cj2[n], t);
                    t = fmaf(-k3v, cj3[n], t);
                    em[m][n][rr] = t;
                }
            }
        // rhs forward (8 owner lanes) + dvec/yfwd (tid 0)
        if (wc == 0 && lr == 0) {
            float fy0 = yLds[k0];
            float fy1 = yLds[k0+1] - l10 * fy0;
            float fy2 = yLds[k0+2] - l20 * fy0 - l21 * fy1;
            float fy3 = yLds[k0+3] - l30 * fy0 - l31 * fy1 - l32 * fy2;
            #pragma unroll
            for (int m = 0; m < 4; ++m)
                #pragma unroll
                for (int rr = 0; rr < 4; ++rr) {
                    int i = wr * 64 + m * 16 + lq * 4 + rr;
                    if (i > k0 + 3) {
                        float4 rv = *(const float4*)&pbufT[par][i][0];
                        float yv = yLds[i];
                        yv = fmaf(-rv.x * i0, fy0, yv);
                        yv = fmaf(-rv.y * i1, fy1, yv);
                        yv = fmaf(-rv.z * i2, fy2, yv);
                        yv = fmaf(-rv.w * i3, fy3, yv);
                        yLds[i] = yv;
                    }
                }
            if (tid == 0) {
                dvec[k0] = d0; dvec[k0+1] = d1; dvec[k0+2] = d2; dvec[k0+3] = d3;
                yfwd[k0] = fy0; yfwd[k0+1] = fy1; yfwd[k0+2] = fy2; yfwd[k0+3] = fy3;
            }
        }
    }
    __syncthreads();
    if (tid < NN) yLds[tid] = yfwd[tid];     // consolidated forward-solved rhs
    __syncthreads();

    // ---- backward rank-4 (1 barrier per 4 pivots) ----
    for (int kb = 31; kb >= 0; --kb) {
        const int k0 = kb * 4;
        const int par = kb & 1;
        {
            int q = lr - (k0 & 15);
            if (wc == (k0 >> 6) && q >= 0 && q < 4) {      // publish factored cols
                #pragma unroll
                for (int nn = 0; nn < 4; ++nn)
                    if (nn == ((k0 >> 4) & 3)) {
                        #pragma unroll
                        for (int m = 0; m < 4; ++m)
                            #pragma unroll
                            for (int r = 0; r < 4; ++r)
                                pbufT[par][wr * 64 + m * 16 + lq * 4 + r][q] = em[m][nn][r];
                    }
            }
        }
        __syncthreads();
        float w3 = yLds[k0+3] / dvec[k0+3];
        float w2 = (yLds[k0+2] - pbufT[par][k0+2][3] * w3) / dvec[k0+2];
        float w1 = (yLds[k0+1] - pbufT[par][k0+1][2] * w2 - pbufT[par][k0+1][3] * w3) / dvec[k0+1];
        float w0 = (yLds[k0]   - pbufT[par][k0][1] * w1 - pbufT[par][k0][2] * w2
                               - pbufT[par][k0][3] * w3) / dvec[k0];
        if (tid == 0) { wvec[k0] = w0; wvec[k0+1] = w1; wvec[k0+2] = w2; wvec[k0+3] = w3; }
        if (tid < k0) {
            float4 pv = *(const float4*)&pbufT[par][tid][0];   // one b128 per thread
            float yv = yLds[tid];
            yv = fmaf(-pv.x, w0, yv);
            yv = fmaf(-pv.y, w1, yv);
            yv = fmaf(-pv.z, w2, yv);
            yv = fmaf(-pv.w, w3, yv);
            yLds[tid] = yv;
        }
    }
    __syncthreads();

    float p1 = 0.f, p2 = 0.f;
    if (tid < NN) {
        float w = wvec[tid];
        float nyv = trainy[idxs[tid]] + 0.01f * noise[(size_t)b * NN + tid] - ymean;
        p1 = w * nyv;
        p2 = w * c0v[tid];
    }
    for (int off = 32; off; off >>= 1) {
        p1 += __shfl_down(p1, off, 64);
        p2 += __shfl_down(p2, off, 64);
    }
    if ((tid & 63) == 0) { red[wv * 2] = p1; red[wv * 2 + 1] = p2; }
    __syncthreads();
    if (tid == 0) {
        out[b]        = (red[0] + red[2] + red[4] + red[6]) + ymean;
        out[B_SZ + b] = av - (red[1] + red[3] + red[5] + red[7]);
    }
}

extern "C" void kernel_launch(void* const* d_in, const int* in_sizes, int n_in,
                              void* d_out, int out_size, void* d_ws, size_t ws_size,
                              hipStream_t stream) {
    const float* x      = (const float*)d_in[0];
    const float* trainX = (const float*)d_in[1];
    const float* trainy = (const float*)d_in[2];
    const float* noise  = (const float*)d_in[3];
    const float* lp     = (const float*)d_in[4];
    const float* ap     = (const float*)d_in[5];
    const float* ymp    = (const float*)d_in[6];
    float* out = (float*)d_out;

    char* ws = (char*)d_ws;
    size_t off = 0;
    auto alloc = [&](size_t bytes) {
        void* p = ws + off;
        off = (off + bytes + 255) & ~(size_t)255;
        return p;
    };
    float* tt   = (float*)alloc((size_t)N_TRAIN * 4);
    float* xx   = (float*)alloc((size_t)B_SZ * 4);
    int*   nidb = (int*)  alloc((size_t)B_SZ * NN * 4);
    float* nsqb = (float*)alloc((size_t)B_SZ * NN * 4);
    u16*   Ah   = (u16*)  alloc((size_t)B_SZ * D_DIM * 2);
    u16*   Bh   = (u16*)  alloc((size_t)N_TRAIN * D_DIM * 2);
    u16*   Bl   = (u16*)  alloc((size_t)N_TRAIN * D_DIM * 2);
    size_t distBytes = (ws_size > off) ? (ws_size - off) : 0;
    u16* distu = (u16*)(ws + off);
    int R = (int)(distBytes / ((size_t)N_PAD * 2));
    if (R > B_SZ) R = B_SZ;      // single chunk if ws allows (k2 occupancy 4/CU)
    if (R < 1) R = 1;

    {
        int waves = N_TRAIN + B_SZ;
        kprep<<<(waves + 3) / 4, 256, 0, stream>>>(trainX, x, tt, xx, Bh, Bl, Ah);
    }

    for (int r0 = 0; r0 < B_SZ; r0 += R) {
        int rc = (B_SZ - r0 < R) ? (B_SZ - r0) : R;
        dim3 g1((N_TRAIN + 127) / 128, (rc + 127) / 128);
        k1m<<<g1, 256, 0, stream>>>(Ah, Bh, xx, tt, distu, r0, rc);
        k2_select<<<rc, 256, 0, stream>>>(distu, r0, x, trainX, xx, tt, nidb, nsqb);
    }
    k3_solve<<<B_SZ, 256, 0, stream>>>(Bh, Bl, trainy, noise, tt, nidb, nsqb,
                                       lp, ap, ymp, out);
}